// Round 11
// baseline (245.689 us; speedup 1.0000x reference)
//
#include <hip/hip_runtime.h>
#include <math.h>

#define HW_ 4096
#define N_ 16384
#define RS2 1168  // LDS B-tile row stride: 18 ks * 64 B + 16 pad -> total 37,376 B (r8-proven 2 blk/CU)

typedef _Float16 f16x4 __attribute__((ext_vector_type(4)));
typedef _Float16 f16x8 __attribute__((ext_vector_type(8)));
typedef float f32x4 __attribute__((ext_vector_type(4)));
typedef unsigned short u16x8 __attribute__((ext_vector_type(8)));

// ws layout (bytes):
//   Wt    f16 [4cb][18ks][256o][32c] @ 0          1,179,648
//         (c = cb*64 + (ks&1)*32 + cloc, k = ks>>1)
//   Woff  f16 [4cb][18ks][32d][32c]  @ 1,179,648    147,456
//   scale f32 [256]                  @ 1,327,104      1,024
//   shift f32 [256]                  @ 1,328,128      1,024
//   xT    f16 [4b][4096hw][256c]     @ 1,329,152  8,388,608
//   total 9,717,760

static __device__ __forceinline__ unsigned short f2h(float f) {
  _Float16 h = (_Float16)f;
  return __builtin_bit_cast(unsigned short, h);
}
static __device__ __forceinline__ f32x4 madv(f32x4 a, float s, f32x4 c) {
  c.x = fmaf(a.x, s, c.x);
  c.y = fmaf(a.y, s, c.y);
  c.z = fmaf(a.z, s, c.z);
  c.w = fmaf(a.w, s, c.w);
  return c;
}

// ---------- transpose x[b][c][hw] f32 -> xT[b][hw][c] f16 (1024 blocks, 256 thr) ----------
__global__ __launch_bounds__(256) void transp_kernel(const float* __restrict__ x,
                                                     _Float16* __restrict__ xT) {
  __shared__ float t[64][65];
  int bid = blockIdx.x;
  int b = bid >> 8, cg = (bid >> 6) & 3, h = bid & 63;
  int tid = threadIdx.x;
  int l16 = tid & 15, r16 = tid >> 4;  // r16 0..15
  const float* xs = x + (size_t)(b * 256 + cg * 64) * HW_ + h * 64;
#pragma unroll
  for (int j = 0; j < 4; ++j) {
    int c = j * 16 + r16;
    f32x4 v = *(const f32x4*)(xs + (size_t)c * HW_ + l16 * 4);
    t[c][l16 * 4 + 0] = v.x;
    t[c][l16 * 4 + 1] = v.y;
    t[c][l16 * 4 + 2] = v.z;
    t[c][l16 * 4 + 3] = v.w;
  }
  __syncthreads();
  _Float16* xd = xT + (size_t)(b * HW_ + h * 64) * 256 + cg * 64;
#pragma unroll
  for (int j = 0; j < 4; ++j) {
    int w2 = j * 16 + r16;
    f16x4 v;
#pragma unroll
    for (int i = 0; i < 4; ++i) v[i] = (_Float16)t[l16 * 4 + i][w2];
    *(f16x4*)(xd + (size_t)w2 * 256 + l16 * 4) = v;
  }
}

// ---------- weight prep (256 blocks = one o each, 256 thr) ----------
__global__ __launch_bounds__(256) void wprep_kernel(
    const float* __restrict__ weight, const float* __restrict__ w_off,
    const float* __restrict__ bias, const float* __restrict__ gamma,
    const float* __restrict__ beta, const float* __restrict__ rmean,
    const float* __restrict__ rvar, unsigned short* __restrict__ Wt,
    unsigned short* __restrict__ Woff, float* __restrict__ scale,
    float* __restrict__ shift) {
  int o = blockIdx.x, tid = threadIdx.x;
  __shared__ unsigned short wl[2304];
  __shared__ unsigned short wol[2304];
  const float* wrow = weight + (size_t)o * 2304;
  const float* worow = w_off + (size_t)o * 2304;  // dereferenced only when o<27
  bool do_off = (o < 32);
#pragma unroll
  for (int j = 0; j < 9; ++j) {
    int flat = tid + j * 256;  // = c*9 + k, coalesced read
    int c = flat / 9, k = flat - 9 * c;
    int cb = c >> 6, cloc = c & 31;
    int ks = (k << 1) | ((c >> 5) & 1);
    int dst = (cb * 18 + ks) * 32 + cloc;
    wl[dst] = f2h(wrow[flat]);
    if (do_off) wol[dst] = f2h((o < 27) ? worow[flat] : 0.f);
  }
  __syncthreads();
  for (int it = tid; it < 288; it += 256) {
    int chunk = it >> 2, part = it & 3;
    *(u16x8*)&Wt[((size_t)chunk * 256 + o) * 32 + part * 8] =
        *(const u16x8*)&wl[chunk * 32 + part * 8];
    if (do_off)
      *(u16x8*)&Woff[((size_t)chunk * 32 + o) * 32 + part * 8] =
          *(const u16x8*)&wol[chunk * 32 + part * 8];
  }
  if (o == 0) {
    float inv = rsqrtf(rvar[tid] + 1e-5f);
    float sc = gamma[tid] * inv;
    scale[tid] = sc;
    shift[tid] = beta[tid] + sc * (bias[tid] - rmean[tid]);
  }
}

// ---------- fused: offset-conv MFMA -> pk/wgt -> sample+GEMM+BN+ReLU ----------
// 512 blocks (32 px each, target 2 blk/CU), 512 thr = 8 waves, pinned 4 waves/EU
// (VGPR budget 128 -> no r8-style 64-reg clamp + scratch spills).
// LDS = B-tile only (37,376 B, r8-proven co-residency size); pk/w4 staged through
// an aliased scratch region then held in registers (r4-proven, no spill at 128).
__global__ __launch_bounds__(512) __attribute__((amdgpu_waves_per_eu(4, 4))) void fused_kernel(
    const _Float16* __restrict__ xT, const unsigned short* __restrict__ Wt,
    const unsigned short* __restrict__ Woff, const float* __restrict__ b_off,
    const float* __restrict__ scale, const float* __restrict__ shift,
    float* __restrict__ out) {
  __shared__ __align__(16) char smem[32 * RS2];          // 37,376 B
  float* om_lds = (float*)smem;                          // [32d][32px]   (phase 1/2 only)
  unsigned int* pk_lds = (unsigned int*)(smem + 4096);   // [9][32]       (phase 2 only)
  float* w4_lds = (float*)(smem + 5248);                 // [9][32][4]    (phase 2 only)

  int bid = blockIdx.x;
  int swz = (bid & 7) * 64 + (bid >> 3);  // XCD-chunked, bijective for 512
  int nbase = swz * 32;
  int b = nbase >> 12;
  int h = (nbase >> 6) & 63;
  int wb = nbase & 32;  // 0 or 32

  int tid = threadIdx.x;
  int lane = tid & 63;
  int wv = tid >> 6;
  int m15 = lane & 15, q = lane >> 4;
  int sn = tid >> 4;  // staging pixel 0..31
  int cs = tid & 15;  // staging 4-channel group (of 64c chunk)

  const char* xb = (const char*)xT + (size_t)b * (HW_ * 512);
  char* ldr = smem + sn * RS2 + ((cs >> 3) << 6) + (cs & 7) * 8;

  // ======== phase 1: offset conv om[27..32][32px] via MFMA (waves 0..3) ========
  int mf = (wv >> 1) & 1, nf1 = wv & 1;
  f32x4 aoff = (f32x4){0.f, 0.f, 0.f, 0.f};
  for (int cb = 0; cb < 4; ++cb) {
    {  // stage direct 3x3 patch chunk (f16 copy, no convert)
      const char* xc = xb + cb * 128 + cs * 8;
#pragma unroll
      for (int k = 0; k < 9; ++k) {
        int ky = k / 3, kx = k - 3 * (k / 3);
        int yy = h + ky - 1, xx = wb + sn + kx - 1;
        f16x4 v = (f16x4){0, 0, 0, 0};
        if (((unsigned)yy < 64u) && ((unsigned)xx < 64u))
          v = *(const f16x4*)(xc + (size_t)(yy * 64 + xx) * 512);
        *(f16x4*)(ldr + k * 128) = v;
      }
    }
    __syncthreads();
    if (wv < 4) {
#pragma unroll
      for (int ks = 0; ks < 18; ++ks) {
        f16x8 a = *(const f16x8*)(Woff + ((cb * 18 + ks) * 32 + mf * 16 + m15) * 32 + q * 8);
        f16x8 bb = *(const f16x8*)(smem + (nf1 * 16 + m15) * RS2 + ks * 64 + q * 16);
        aoff = __builtin_amdgcn_mfma_f32_16x16x32_f16(a, bb, aoff, 0, 0, 0);
      }
    }
    __syncthreads();
  }
  if (wv < 4) {
#pragma unroll
    for (int r = 0; r < 4; ++r)
      om_lds[(mf * 16 + q * 4 + r) * 32 + nf1 * 16 + m15] = aoff[r];
  }
  __syncthreads();

  // ======== phase 2: pk + bilinear*mask corner weights (aliased LDS scratch) ========
  if (tid < 288) {
    int k = tid >> 5, pxl = tid & 31;
    float dy = om_lds[k * 32 + pxl] + b_off[k];
    float dx = om_lds[(k + 9) * 32 + pxl] + b_off[k + 9];
    float z = om_lds[(k + 18) * 32 + pxl] + b_off[k + 18];
    float ms = 1.f / (1.f + expf(-z));
    int ky = k / 3, kx = k - 3 * ky;
    float py = dy + (float)(h - 1 + ky);
    float pxf = dx + (float)(wb + pxl - 1 + kx);
    float fy0 = floorf(py), fx0 = floorf(pxf);
    float ly = py - fy0, lx = pxf - fx0;
    int iy0 = (int)fy0, ix0 = (int)fx0;
    bool vy0 = (iy0 >= 0) && (iy0 < 64);
    bool vy1 = (iy0 >= -1) && (iy0 < 63);
    bool vx0 = (ix0 >= 0) && (ix0 < 64);
    bool vx1 = (ix0 >= -1) && (ix0 < 63);
    int yA = min(max(iy0, 0), 63), yB = min(max(iy0 + 1, 0), 63);
    int xA = min(max(ix0, 0), 63), xB = min(max(ix0 + 1, 0), 63);
    pk_lds[k * 32 + pxl] = (unsigned)(yA * 64 + xA) | ((unsigned)(xB - xA) << 12) |
                           ((unsigned)(yB - yA) << 13);
    float* wp = w4_lds + (k * 32 + pxl) * 4;
    wp[0] = (1.f - ly) * (1.f - lx) * ms * ((vy0 && vx0) ? 1.f : 0.f);
    wp[1] = (1.f - ly) * lx * ms * ((vy0 && vx1) ? 1.f : 0.f);
    wp[2] = ly * (1.f - lx) * ms * ((vy1 && vx0) ? 1.f : 0.f);
    wp[3] = ly * lx * ms * ((vy1 && vx1) ? 1.f : 0.f);
  }
  __syncthreads();

  // per-thread sampling params for its staging pixel -> registers (static indexing)
  unsigned int pkv[9];
  float wf[9][4];
#pragma unroll
  for (int k = 0; k < 9; ++k) {
    pkv[k] = pk_lds[k * 32 + sn];
#pragma unroll
    for (int j = 0; j < 4; ++j) wf[k][j] = w4_lds[(k * 32 + sn) * 4 + j];
  }

  // ======== phase 3: sample + main GEMM, register-pipelined staging ========
  f32x4 acc[2][2];
#pragma unroll
  for (int mfi = 0; mfi < 2; ++mfi)
#pragma unroll
    for (int nf = 0; nf < 2; ++nf) acc[mfi][nf] = (f32x4){0.f, 0.f, 0.f, 0.f};

  f16x4 sv[9];
  // f16 corners (8B loads), f32 blend, f16 result
#define GATHER(CB)                                                      \
  {                                                                     \
    const char* xc = xb + (CB) * 128 + cs * 8;                          \
    _Pragma("unroll") for (int k = 0; k < 9; ++k) {                     \
      unsigned pv = pkv[k];                                             \
      const char* p00 = xc + ((size_t)(pv & 0xFFFu) << 9);              \
      int dxb = (int)(pv & 0x1000u) >> 3;  /* 0 or 512   */             \
      int dyb = (int)(pv & 0x2000u) << 2;  /* 0 or 32768 */             \
      f16x4 c00 = *(const f16x4*)(p00);                                 \
      f16x4 c01 = *(const f16x4*)(p00 + dxb);                           \
      f16x4 c10 = *(const f16x4*)(p00 + dyb);                           \
      f16x4 c11 = *(const f16x4*)(p00 + dyb + dxb);                     \
      f32x4 v = (f32x4){0.f, 0.f, 0.f, 0.f};                            \
      v = madv(__builtin_convertvector(c00, f32x4), wf[k][0], v);       \
      v = madv(__builtin_convertvector(c01, f32x4), wf[k][1], v);       \
      v = madv(__builtin_convertvector(c10, f32x4), wf[k][2], v);       \
      v = madv(__builtin_convertvector(c11, f32x4), wf[k][3], v);       \
      sv[k] = __builtin_convertvector(v, f16x4);                        \
    }                                                                   \
  }

  GATHER(0);
  __syncthreads();  // pk/w4 register copies complete before B-tile overwrite
  for (int cb = 0; cb < 4; ++cb) {
    {
#pragma unroll
      for (int k = 0; k < 9; ++k) *(f16x4*)(ldr + k * 128) = sv[k];
    }
    __syncthreads();
    if (cb < 3) GATHER(cb + 1);  // loads in flight under the MFMA block below
    {
      const unsigned short* wtk = Wt + (size_t)(cb * 18) * 8192 + (wv * 32 + m15) * 32 + q * 8;
#pragma unroll
      for (int ks = 0; ks < 18; ++ks) {
        const unsigned short* wp2 = wtk + ks * 8192;
        f16x8 a0 = *(const f16x8*)(wp2);
        f16x8 a1 = *(const f16x8*)(wp2 + 512);  // +16 o-rows
#pragma unroll
        for (int nf = 0; nf < 2; ++nf) {
          f16x8 bb = *(const f16x8*)(smem + (nf * 16 + m15) * RS2 + ks * 64 + q * 16);
          acc[0][nf] = __builtin_amdgcn_mfma_f32_16x16x32_f16(a0, bb, acc[0][nf], 0, 0, 0);
          acc[1][nf] = __builtin_amdgcn_mfma_f32_16x16x32_f16(a1, bb, acc[1][nf], 0, 0, 0);
        }
      }
    }
    __syncthreads();
  }

  // ======== epilogue: BN + ReLU; C/D: col=lane&15 (px), row=(lane>>4)*4+r (o) ========
  float* ob = out + (size_t)(b * 256) * HW_ + h * 64 + wb;
#pragma unroll
  for (int mfi = 0; mfi < 2; ++mfi)
#pragma unroll
    for (int r = 0; r < 4; ++r) {
      int o = wv * 32 + mfi * 16 + q * 4 + r;
      float sc = scale[o], sh = shift[o];
#pragma unroll
      for (int nf = 0; nf < 2; ++nf) {
        float vv = fmaxf(fmaf(acc[mfi][nf][r], sc, sh), 0.f);
        ob[(size_t)o * HW_ + nf * 16 + m15] = vv;
      }
    }
}

extern "C" void kernel_launch(void* const* d_in, const int* in_sizes, int n_in,
                              void* d_out, int out_size, void* d_ws, size_t ws_size,
                              hipStream_t stream) {
  (void)in_sizes; (void)n_in; (void)out_size; (void)ws_size;
  const float* x = (const float*)d_in[0];
  const float* w_off = (const float*)d_in[1];
  const float* b_off = (const float*)d_in[2];
  const float* weight = (const float*)d_in[3];
  const float* bias = (const float*)d_in[4];
  const float* gamma = (const float*)d_in[5];
  const float* beta = (const float*)d_in[6];
  const float* rmean = (const float*)d_in[7];
  const float* rvar = (const float*)d_in[8];
  char* ws = (char*)d_ws;
  unsigned short* Wt = (unsigned short*)ws;
  unsigned short* Woff = (unsigned short*)(ws + 1179648);
  float* scale = (float*)(ws + 1327104);
  float* shift = (float*)(ws + 1328128);
  _Float16* xT = (_Float16*)(ws + 1329152);
  float* out = (float*)d_out;

  transp_kernel<<<dim3(1024), dim3(256), 0, stream>>>(x, xT);
  wprep_kernel<<<dim3(256), dim3(256), 0, stream>>>(weight, w_off, bias, gamma, beta,
                                                    rmean, rvar, Wt, Woff, scale, shift);
  fused_kernel<<<dim3(512), dim3(512), 0, stream>>>(xT, Wt, Woff, b_off, scale, shift, out);
}